// Round 16
// baseline (305.710 us; speedup 1.0000x reference)
//
#include <hip/hip_runtime.h>

// AnatomicalConsistencyLoss: fused separable-Sobel magnitude + cosine loss.
// pred/target (2,1,160,160,160) f32 -> scalar f32.
// R16 = R15 with two occupancy/overhead fixes:
// (1) DC 16->10: 1600 blocks -> 25 waves/CU cap (78%, was 15.6/32=49%).
//     Grid size was the occupancy cap (all blocks co-resident, VGPR 52).
//     Cost: warm-up planes 12.5%->16.7% of work -- TLP gain dominates.
// (2) single-kernel finalization: out = 0.2 + 0.2*(m-c)/N, accumulated via
//     per-block fp32 atomicAdd (device-scope; order-noise ~1e-3 << 0.2625
//     threshold); d_out zeroed by hipMemsetAsync (graph-capturable). Saves
//     the second launch + inter-kernel gap (~3us of the 34us bench).
// Body identical to R15: barrier-free, f4 misaligned row loads, hoisted
// zero-init, balanced consume-then-reissue prefetch, streaming pending-sum,
// XCD-chunked bijective swizzle, fused transcendentals, packed-v2 math.

constexpr int Dd = 160, Hh = 160, Ww = 160;
constexpr int TW = 32, TH = 16, DC = 10;
constexpr int NTX = Ww / TW;                 // 5
constexpr int NTY = Hh / TH;                 // 10
constexpr int NTZ = Dd / DC;                 // 16
constexpr int NBLOCKS = NTX * NTY * NTZ * 2; // 1600
constexpr int NXCD = 8;
constexpr int CHUNK = NBLOCKS / NXCD;        // 200 (1600 % 8 == 0: bijective)
constexpr int PLANES = DC + 2;               // 12
constexpr int PLSZ = Hh * Ww;                // 25600
constexpr float INV_NVOX = 1.0f / 8192000.0f;

// native clang vectors: v2 arithmetic lowers to packed dual-f32 VOP3P
typedef float v2 __attribute__((ext_vector_type(2)));
typedef float v4 __attribute__((ext_vector_type(4), aligned(4)));  // dword-aligned dwordx4

__attribute__((amdgpu_waves_per_eu(4)))
__global__ __launch_bounds__(256)
void acl_fused(const float* __restrict__ pred, const float* __restrict__ targ,
               float* __restrict__ out)
{
    __shared__ float rred[8];   // final reduction only; no LDS in main loop

    const int tid = threadIdx.x;
    const int gx = tid & 15;          // x-group of 2 output cols
    const int r  = tid >> 4;          // row 0..15

    // ---- XCD-chunked bijective swizzle + decode (zt fastest, wt, ht, b) ----
    const int bid  = blockIdx.x;
    const int swz  = (bid % NXCD) * CHUNK + bid / NXCD;   // XCD k owns [k*200,...)
    const int zt   = swz % NTZ;
    const int t1   = swz / NTZ;
    const int wt   = t1 % NTX;
    const int t2   = t1 / NTX;
    const int ht   = t2 % NTY;
    const int b    = t2 / NTY;           // 0..1

    const int x0 = wt * TW, y0 = ht * TH;
    const int z0 = zt * DC;
    const size_t base = (size_t)b * ((size_t)Dd * PLSZ);
    const float* __restrict__ pv = pred + base;
    const float* __restrict__ tv = targ + base;

    const int X = x0 + 2 * gx;
    const bool blkLo = (x0 == 0);
    const bool blkHi = (x0 + TW == Ww);
    const bool fixLo = blkLo && (gx == 0);    // load clamped +1, shift-right fixup
    const bool fixHi = blkHi && (gx == 15);   // load clamped -1, shift-left fixup
    const int xoff = X - 1 + (fixLo ? 1 : 0) - (fixHi ? 1 : 0);

    const int gym = y0 + r - 1;
    const int gyp = y0 + r + 1;
    const bool yokm = (gym >= 0);     // loop-invariant per thread
    const bool yokp = (gyp < Hh);     // loop-invariant per thread
    const int om = gym * Ww + xoff;
    const int oc = (y0 + r) * Ww + xoff;
    const int op = gyp * Ww + xoff;

    const v2 z2 = {0.f, 0.f};
    const v4 z4 = {0.f, 0.f, 0.f, 0.f};

    // streaming pending partial gradients (named v2 scalars only)
    v2 P1x = z2, P1y = z2, P1z = z2, P2x = z2, P2y = z2, P2z = z2;  // pred
    v2 T1x = z2, T1y = z2, T1z = z2, T2x = z2, T2y = z2, T2z = z2;  // targ
    v2 accm = z2, accc = z2;

    // prefetch registers; zero-init ONCE (invalid-row lanes stay zero forever)
    v4 mP = z4, cP = z4, pP = z4, mT = z4, cT = z4, pT = z4;

    auto issueP = [&](int p) {
        const int gz = z0 - 1 + p;
        if ((unsigned)gz < (unsigned)Dd) {            // wave-uniform branch
            const float* pz = pv + (ptrdiff_t)gz * PLSZ;
            if (yokm) mP = *(const v4*)(pz + om);
            cP = *(const v4*)(pz + oc);
            if (yokp) pP = *(const v4*)(pz + op);
        } else {   // only boundary planes of edge-zt blocks
            mP = z4; cP = z4; pP = z4;
        }
    };
    auto issueT = [&](int p) {
        const int gz = z0 - 1 + p;
        if ((unsigned)gz < (unsigned)Dd) {
            const float* tz = tv + (ptrdiff_t)gz * PLSZ;
            if (yokm) mT = *(const v4*)(tz + om);
            cT = *(const v4*)(tz + oc);
            if (yokp) pT = *(const v4*)(tz + op);
        } else {
            mT = z4; cT = z4; pT = z4;
        }
    };

    // volume-edge fixup: only edge blocks pay (block-uniform branches)
    auto fixup = [&](v4 v) -> v4 {
        if (blkLo) { const v4 s = {0.f, v.x, v.y, v.z}; if (fixLo) v = s; }
        if (blkHi) { const v4 s = {v.y, v.z, v.w, 0.f}; if (fixHi) v = s; }
        return v;
    };

    // horizontal + vertical combos, packed v2 arithmetic
    auto consumeVol = [&](v4 m, v4 c, v4 p, v2& A, v2& B, v2& C) {
        m = fixup(m); c = fixup(c); p = fixup(p);
        const v2 HSm = m.xy + 2.f*m.yz + m.zw;   // smooth_x, row y-1
        const v2 HDm = m.zw - m.xy;              // deriv_x,  row y-1
        const v2 HS0 = c.xy + 2.f*c.yz + c.zw;
        const v2 HD0 = c.zw - c.xy;
        const v2 HSp = p.xy + 2.f*p.yz + p.zw;
        const v2 HDp = p.zw - p.xy;
        A = HSm + 2.f*HS0 + HSp;   // sm_y(sm_x) -> z-deriv path
        B = HDm + 2.f*HD0 + HDp;   // sm_y(d_x)  -> x-gradient
        C = HSp - HSm;             // d_y(sm_x)  -> y-gradient
    };

    issueP(0);
    issueT(0);

    for (int p = 0; p < PLANES; ++p) {
        v2 A, B, C;

        // pred: consume, then immediately refill the SAME set for p+1
        consumeVol(mP, cP, pP, A, B, C);
        const v2 fpx = P1x + B, fpy = P1y + C, fpz = A - P1z;
        P1x = 2.f*B + P2x;  P1y = 2.f*C + P2y;  P1z = P2z;
        P2x = B;  P2y = C;  P2z = A;
        if (p + 1 < PLANES) issueP(p + 1);

        // targ: same pattern
        consumeVol(mT, cT, pT, A, B, C);
        const v2 ftx = T1x + B, fty = T1y + C, ftz = A - T1z;
        T1x = 2.f*B + T2x;  T1y = 2.f*C + T2y;  T1z = T2z;
        T2x = B;  T2y = C;  T2z = A;
        if (p + 1 < PLANES) issueT(p + 1);

        if (p >= 2) {   // output plane z0 + (p-2) finalized
            // fused: (pm-tm)^2 = a+b-2*sqrt(a*b);  rsq(np2)*rsq(nt2)=rsq(np2*nt2)
            const v2 np2 = fpx*fpx + fpy*fpy + fpz*fpz;
            const v2 nt2 = ftx*ftx + fty*fty + ftz*ftz;
            const v2 a  = np2 + 1e-8f;
            const v2 bb = nt2 + 1e-8f;
            const v2 ab = a * bb;
            v2 rt;
            rt.x = __builtin_amdgcn_sqrtf(ab.x);
            rt.y = __builtin_amdgcn_sqrtf(ab.y);
            accm += a + bb - 2.f*rt;
            const v2 dt = fpx*ftx + fpy*fty + fpz*ftz;
            v2 pr = np2 * nt2;
            pr.x = fmaxf(pr.x, 1e-30f);
            pr.y = fmaxf(pr.y, 1e-30f);
            v2 rq;
            rq.x = __builtin_amdgcn_rsqf(pr.x);
            rq.y = __builtin_amdgcn_rsqf(pr.y);
            accc += dt * rq;
        }
    }

    // ---- block reduction, then one atomic per block ----
    float am = accm.x + accm.y;
    float ac = accc.x + accc.y;
    #pragma unroll
    for (int off = 32; off >= 1; off >>= 1) {
        am += __shfl_down(am, off);
        ac += __shfl_down(ac, off);
    }
    const int wid = tid >> 6;
    if ((tid & 63) == 0) { rred[wid] = am; rred[4 + wid] = ac; }
    __syncthreads();
    if (tid == 0) {
        const float m = rred[0] + rred[1] + rred[2] + rred[3];
        const float c = rred[4] + rred[5] + rred[6] + rred[7];
        // out = 0.2 + 0.2*(m_total - c_total)/NVOX; block 0 adds the constant
        float contrib = 0.2f * (m - c) * INV_NVOX;
        if (bid == 0) contrib += 0.2f;
        atomicAdd(out, contrib);
    }
}

extern "C" void kernel_launch(void* const* d_in, const int* in_sizes, int n_in,
                              void* d_out, int out_size, void* d_ws, size_t ws_size,
                              hipStream_t stream) {
    const float* pred = (const float*)d_in[0];
    const float* targ = (const float*)d_in[1];
    float* out = (float*)d_out;

    hipMemsetAsync(out, 0, sizeof(float), stream);   // graph-capturable
    acl_fused<<<NBLOCKS, 256, 0, stream>>>(pred, targ, out);
}

// Round 17
// 50.949 us; speedup vs baseline: 6.0003x; 6.0003x over previous
//
#include <hip/hip_runtime.h>

// AnatomicalConsistencyLoss: fused separable-Sobel magnitude + cosine loss.
// pred/target (2,1,160,160,160) f32 -> scalar f32.
// R17 = R16 with the plane loop PINNED ROLLED (#pragma unroll 1).
// R16's 305us disaster: shortening PLANES 18->12 crossed LLVM's unroll
// threshold; the unrolled loop put several planes' prefetch sets in flight
// at once -> live state blew past the 64-VGPR cap -> 470MB of spill traffic.
// With unroll pinned, per-iteration state is the proven ~52-dword set.
// Retains R16's two levers: DC=10 (1600 blocks -> 25 waves/CU occupancy cap,
// was 15.6) and single-kernel atomicAdd finalization (no second launch).
// Body otherwise identical to R15.

constexpr int Dd = 160, Hh = 160, Ww = 160;
constexpr int TW = 32, TH = 16, DC = 10;
constexpr int NTX = Ww / TW;                 // 5
constexpr int NTY = Hh / TH;                 // 10
constexpr int NTZ = Dd / DC;                 // 16
constexpr int NBLOCKS = NTX * NTY * NTZ * 2; // 1600
constexpr int NXCD = 8;
constexpr int CHUNK = NBLOCKS / NXCD;        // 200 (1600 % 8 == 0: bijective)
constexpr int PLANES = DC + 2;               // 12
constexpr int PLSZ = Hh * Ww;                // 25600
constexpr float INV_NVOX = 1.0f / 8192000.0f;

// native clang vectors: v2 arithmetic lowers to packed dual-f32 VOP3P
typedef float v2 __attribute__((ext_vector_type(2)));
typedef float v4 __attribute__((ext_vector_type(4), aligned(4)));  // dword-aligned dwordx4

__attribute__((amdgpu_waves_per_eu(4)))
__global__ __launch_bounds__(256)
void acl_fused(const float* __restrict__ pred, const float* __restrict__ targ,
               float* __restrict__ out)
{
    __shared__ float rred[8];   // final reduction only; no LDS in main loop

    const int tid = threadIdx.x;
    const int gx = tid & 15;          // x-group of 2 output cols
    const int r  = tid >> 4;          // row 0..15

    // ---- XCD-chunked bijective swizzle + decode (zt fastest, wt, ht, b) ----
    const int bid  = blockIdx.x;
    const int swz  = (bid % NXCD) * CHUNK + bid / NXCD;   // XCD k owns [k*200,...)
    const int zt   = swz % NTZ;
    const int t1   = swz / NTZ;
    const int wt   = t1 % NTX;
    const int t2   = t1 / NTX;
    const int ht   = t2 % NTY;
    const int b    = t2 / NTY;           // 0..1

    const int x0 = wt * TW, y0 = ht * TH;
    const int z0 = zt * DC;
    const size_t base = (size_t)b * ((size_t)Dd * PLSZ);
    const float* __restrict__ pv = pred + base;
    const float* __restrict__ tv = targ + base;

    const int X = x0 + 2 * gx;
    const bool blkLo = (x0 == 0);
    const bool blkHi = (x0 + TW == Ww);
    const bool fixLo = blkLo && (gx == 0);    // load clamped +1, shift-right fixup
    const bool fixHi = blkHi && (gx == 15);   // load clamped -1, shift-left fixup
    const int xoff = X - 1 + (fixLo ? 1 : 0) - (fixHi ? 1 : 0);

    const int gym = y0 + r - 1;
    const int gyp = y0 + r + 1;
    const bool yokm = (gym >= 0);     // loop-invariant per thread
    const bool yokp = (gyp < Hh);     // loop-invariant per thread
    const int om = gym * Ww + xoff;
    const int oc = (y0 + r) * Ww + xoff;
    const int op = gyp * Ww + xoff;

    const v2 z2 = {0.f, 0.f};
    const v4 z4 = {0.f, 0.f, 0.f, 0.f};

    // streaming pending partial gradients (named v2 scalars only)
    v2 P1x = z2, P1y = z2, P1z = z2, P2x = z2, P2y = z2, P2z = z2;  // pred
    v2 T1x = z2, T1y = z2, T1z = z2, T2x = z2, T2y = z2, T2z = z2;  // targ
    v2 accm = z2, accc = z2;

    // prefetch registers; zero-init ONCE (invalid-row lanes stay zero forever)
    v4 mP = z4, cP = z4, pP = z4, mT = z4, cT = z4, pT = z4;

    auto issueP = [&](int p) {
        const int gz = z0 - 1 + p;
        if ((unsigned)gz < (unsigned)Dd) {            // wave-uniform branch
            const float* pz = pv + (ptrdiff_t)gz * PLSZ;
            if (yokm) mP = *(const v4*)(pz + om);
            cP = *(const v4*)(pz + oc);
            if (yokp) pP = *(const v4*)(pz + op);
        } else {   // only boundary planes of edge-zt blocks
            mP = z4; cP = z4; pP = z4;
        }
    };
    auto issueT = [&](int p) {
        const int gz = z0 - 1 + p;
        if ((unsigned)gz < (unsigned)Dd) {
            const float* tz = tv + (ptrdiff_t)gz * PLSZ;
            if (yokm) mT = *(const v4*)(tz + om);
            cT = *(const v4*)(tz + oc);
            if (yokp) pT = *(const v4*)(tz + op);
        } else {
            mT = z4; cT = z4; pT = z4;
        }
    };

    // volume-edge fixup: only edge blocks pay (block-uniform branches)
    auto fixup = [&](v4 v) -> v4 {
        if (blkLo) { const v4 s = {0.f, v.x, v.y, v.z}; if (fixLo) v = s; }
        if (blkHi) { const v4 s = {v.y, v.z, v.w, 0.f}; if (fixHi) v = s; }
        return v;
    };

    // horizontal + vertical combos, packed v2 arithmetic
    auto consumeVol = [&](v4 m, v4 c, v4 p, v2& A, v2& B, v2& C) {
        m = fixup(m); c = fixup(c); p = fixup(p);
        const v2 HSm = m.xy + 2.f*m.yz + m.zw;   // smooth_x, row y-1
        const v2 HDm = m.zw - m.xy;              // deriv_x,  row y-1
        const v2 HS0 = c.xy + 2.f*c.yz + c.zw;
        const v2 HD0 = c.zw - c.xy;
        const v2 HSp = p.xy + 2.f*p.yz + p.zw;
        const v2 HDp = p.zw - p.xy;
        A = HSm + 2.f*HS0 + HSp;   // sm_y(sm_x) -> z-deriv path
        B = HDm + 2.f*HD0 + HDp;   // sm_y(d_x)  -> x-gradient
        C = HSp - HSm;             // d_y(sm_x)  -> y-gradient
    };

    issueP(0);
    issueT(0);

    #pragma unroll 1   // CRITICAL: rolled loop = one plane's prefetch in flight
    for (int p = 0; p < PLANES; ++p) {
        v2 A, B, C;

        // pred: consume, then immediately refill the SAME set for p+1
        consumeVol(mP, cP, pP, A, B, C);
        const v2 fpx = P1x + B, fpy = P1y + C, fpz = A - P1z;
        P1x = 2.f*B + P2x;  P1y = 2.f*C + P2y;  P1z = P2z;
        P2x = B;  P2y = C;  P2z = A;
        if (p + 1 < PLANES) issueP(p + 1);

        // targ: same pattern
        consumeVol(mT, cT, pT, A, B, C);
        const v2 ftx = T1x + B, fty = T1y + C, ftz = A - T1z;
        T1x = 2.f*B + T2x;  T1y = 2.f*C + T2y;  T1z = T2z;
        T2x = B;  T2y = C;  T2z = A;
        if (p + 1 < PLANES) issueT(p + 1);

        if (p >= 2) {   // output plane z0 + (p-2) finalized
            // fused: (pm-tm)^2 = a+b-2*sqrt(a*b);  rsq(np2)*rsq(nt2)=rsq(np2*nt2)
            const v2 np2 = fpx*fpx + fpy*fpy + fpz*fpz;
            const v2 nt2 = ftx*ftx + fty*fty + ftz*ftz;
            const v2 a  = np2 + 1e-8f;
            const v2 bb = nt2 + 1e-8f;
            const v2 ab = a * bb;
            v2 rt;
            rt.x = __builtin_amdgcn_sqrtf(ab.x);
            rt.y = __builtin_amdgcn_sqrtf(ab.y);
            accm += a + bb - 2.f*rt;
            const v2 dt = fpx*ftx + fpy*fty + fpz*ftz;
            v2 pr = np2 * nt2;
            pr.x = fmaxf(pr.x, 1e-30f);
            pr.y = fmaxf(pr.y, 1e-30f);
            v2 rq;
            rq.x = __builtin_amdgcn_rsqf(pr.x);
            rq.y = __builtin_amdgcn_rsqf(pr.y);
            accc += dt * rq;
        }
    }

    // ---- block reduction, then one atomic per block ----
    float am = accm.x + accm.y;
    float ac = accc.x + accc.y;
    #pragma unroll
    for (int off = 32; off >= 1; off >>= 1) {
        am += __shfl_down(am, off);
        ac += __shfl_down(ac, off);
    }
    const int wid = tid >> 6;
    if ((tid & 63) == 0) { rred[wid] = am; rred[4 + wid] = ac; }
    __syncthreads();
    if (tid == 0) {
        const float m = rred[0] + rred[1] + rred[2] + rred[3];
        const float c = rred[4] + rred[5] + rred[6] + rred[7];
        // out = 0.2 + 0.2*(m_total - c_total)/NVOX; block 0 adds the constant
        float contrib = 0.2f * (m - c) * INV_NVOX;
        if (bid == 0) contrib += 0.2f;
        atomicAdd(out, contrib);
    }
}

extern "C" void kernel_launch(void* const* d_in, const int* in_sizes, int n_in,
                              void* d_out, int out_size, void* d_ws, size_t ws_size,
                              hipStream_t stream) {
    const float* pred = (const float*)d_in[0];
    const float* targ = (const float*)d_in[1];
    float* out = (float*)d_out;

    hipMemsetAsync(out, 0, sizeof(float), stream);   // graph-capturable
    acl_fused<<<NBLOCKS, 256, 0, stream>>>(pred, targ, out);
}

// Round 18
// 32.553 us; speedup vs baseline: 9.3911x; 1.5651x over previous
//
#include <hip/hip_runtime.h>

// AnatomicalConsistencyLoss: fused separable-Sobel magnitude + cosine loss.
// pred/target (2,1,160,160,160) f32 -> scalar f32.
// R18: LDS-staged planes via __builtin_amdgcn_global_load_lds. R12-R17
// established: register prefetch caps in-flight at ~96B/wave (spill wall at
// ~60 live dwords; extra waves refused) -> ~1-1.6 TB/s latency-bound, per
// Little's law. gload_lds escapes it: LDS destination = no VGPR cost for
// in-flight data (2KB/wave here). Per plane: 3 waves issue 2 gload_lds each
// (18 rows x 40 floats x 2 vols, linear lane map, per-lane clamped global
// addrs); one __syncthreads per plane (its vmcnt(0) drain sits AFTER a full
// compute phase of cover). Compute = R15's proven pending-sum + packed-v2
// math reading from LDS; halo garbage zeroed by fixLo/fixHi/yok selects,
// z-boundary planes zeroed wave-uniformly. Geometry = proven R15: DC=16,
// 1000 blocks, XCD-chunked swizzle, two-kernel finalize.

constexpr int Dd = 160, Hh = 160, Ww = 160;
constexpr int TW = 32, TH = 16, DC = 16;
constexpr int NTX = Ww / TW;                 // 5
constexpr int NTY = Hh / TH;                 // 10
constexpr int NTZ = Dd / DC;                 // 10
constexpr int NBLOCKS = NTX * NTY * NTZ * 2; // 1000
constexpr int NXCD = 8;
constexpr int CHUNK = NBLOCKS / NXCD;        // 125
constexpr int PLANES = DC + 2;               // 18
constexpr int PLSZ = Hh * Ww;                // 25600
constexpr double NVOX = 2.0 * Dd * Hh * Ww;  // 8,192,000

constexpr int SPANF = 40;                    // floats staged per row (x0-4..x0+36)
constexpr int SROWS = TH + 2;                // 18 rows staged per plane
constexpr int VOLF  = 768;                   // padded vol region: 3*1024B = 768 floats

typedef float v2 __attribute__((ext_vector_type(2)));
typedef float v4 __attribute__((ext_vector_type(4)));

#define GLD16(g, l)                                                     \
    __builtin_amdgcn_global_load_lds(                                   \
        (const __attribute__((address_space(1))) void*)(g),             \
        (__attribute__((address_space(3))) void*)(l), 16, 0, 0)

__global__ __launch_bounds__(256)
void acl_partial(const float* __restrict__ pred, const float* __restrict__ targ,
                 float2* __restrict__ partial)
{
    __shared__ float sv[2][2][VOLF];   // [zbuf][vol][row*40+col], 24 KB
    __shared__ float rred[8];

    const int tid  = threadIdx.x;
    const int lane = tid & 63;
    const int wid  = tid >> 6;
    const int gx   = tid & 15;        // x-group of 2 output cols
    const int r    = tid >> 4;        // row 0..15

    // ---- XCD-chunked bijective swizzle + decode (zt fastest, wt, ht, b) ----
    const int bid = blockIdx.x;
    const int swz = (bid % NXCD) * CHUNK + bid / NXCD;
    const int zt  = swz % NTZ;
    const int t1  = swz / NTZ;
    const int wt  = t1 % NTX;
    const int t2  = t1 / NTX;
    const int ht  = t2 % NTY;
    const int b   = t2 / NTY;

    const int x0 = wt * TW, y0 = ht * TH;
    const int z0 = zt * DC;
    const size_t base = (size_t)b * ((size_t)Dd * PLSZ);
    const float* __restrict__ pv = pred + base;
    const float* __restrict__ tv = targ + base;

    // ---- staging constants (per-lane, loop-invariant) ----
    // byte offset within vol region covered by this wave's gload_lds
    const int so   = (wid < 3 ? wid : 0) * 1024 + lane * 16;
    int srow = so / 160;  if (srow > SROWS - 1) srow = SROWS - 1;   // row (160B rows)
    const int scol = (so % 160) >> 2;                               // float col, mult of 4
    int sgy = y0 - 1 + srow;  sgy = sgy < 0 ? 0 : (sgy > Hh - 1 ? Hh - 1 : sgy);
    int sgx = x0 - 4 + scol;  sgx = sgx < 0 ? 0 : (sgx > Ww - 4 ? Ww - 4 : sgx);
    const int splaneoff = sgy * Ww + sgx;
    const int ldsoff = wid * 256;                                   // floats

    // ---- consume constants ----
    const bool blkLo = (x0 == 0);
    const bool blkHi = (x0 + TW == Ww);
    const bool fixLo = blkLo && (gx == 0);
    const bool fixHi = blkHi && (gx == 15);
    const bool yokm  = (y0 + r - 1 >= 0);
    const bool yokp  = (y0 + r + 1 < Hh);
    const int  rb    = r * SPANF + 2 * gx + 3;   // col of X-1 in row r

    const v2 z2 = {0.f, 0.f};
    const v4 z4 = {0.f, 0.f, 0.f, 0.f};

    // streaming pending partial gradients (named v2 scalars only)
    v2 P1x = z2, P1y = z2, P1z = z2, P2x = z2, P2y = z2, P2z = z2;
    v2 T1x = z2, T1y = z2, T1z = z2, T2x = z2, T2y = z2, T2z = z2;
    v2 accm = z2, accc = z2;

    auto stage = [&](int p1, int buf) {   // stage plane p1 (z = z0-1+p1)
        if (wid < 3) {
            int gz = z0 - 1 + p1;
            gz = gz < 0 ? 0 : (gz > Dd - 1 ? Dd - 1 : gz);
            const float* gp = pv + (ptrdiff_t)gz * PLSZ + splaneoff;
            const float* gt = tv + (ptrdiff_t)gz * PLSZ + splaneoff;
            GLD16(gp, &sv[buf][0][ldsoff]);
            GLD16(gt, &sv[buf][1][ldsoff]);
        }
    };

    // read 4-float span [X-1..X+2] of one staged row; zero invalid floats
    auto loadRow = [&](const float* S, int idx, bool valid) -> v4 {
        v4 row;
        row.x = fixLo ? 0.f : S[idx];
        row.y = S[idx + 1];
        row.z = S[idx + 2];
        row.w = fixHi ? 0.f : S[idx + 3];
        if (!valid) row = z4;
        return row;
    };

    auto consumeVol = [&](const float* S, v2& A, v2& B, v2& C) {
        const v4 m = loadRow(S, rb,             yokm);
        const v4 c = loadRow(S, rb + SPANF,     true);
        const v4 p = loadRow(S, rb + 2 * SPANF, yokp);
        const v2 HSm = m.xy + 2.f*m.yz + m.zw;
        const v2 HDm = m.zw - m.xy;
        const v2 HS0 = c.xy + 2.f*c.yz + c.zw;
        const v2 HD0 = c.zw - c.xy;
        const v2 HSp = p.xy + 2.f*p.yz + p.zw;
        const v2 HDp = p.zw - p.xy;
        A = HSm + 2.f*HS0 + HSp;   // sm_y(sm_x) -> z-deriv path
        B = HDm + 2.f*HD0 + HDp;   // sm_y(d_x)  -> x-gradient
        C = HSp - HSm;             // d_y(sm_x)  -> y-gradient
    };

    stage(0, 0);
    __syncthreads();     // plane 0 staged (vmcnt drained by syncthreads)

    #pragma unroll 1
    for (int p = 0; p < PLANES; ++p) {
        const int buf = p & 1;

        // issue next plane's staging: flies under this plane's compute
        if (p + 1 < PLANES) stage(p + 1, buf ^ 1);

        const bool zok = ((unsigned)(z0 - 1 + p) < (unsigned)Dd);   // wave-uniform

        v2 A, B, C;
        consumeVol(&sv[buf][0][0], A, B, C);
        if (!zok) { A = z2; B = z2; C = z2; }
        const v2 fpx = P1x + B, fpy = P1y + C, fpz = A - P1z;
        P1x = 2.f*B + P2x;  P1y = 2.f*C + P2y;  P1z = P2z;
        P2x = B;  P2y = C;  P2z = A;

        consumeVol(&sv[buf][1][0], A, B, C);
        if (!zok) { A = z2; B = z2; C = z2; }
        const v2 ftx = T1x + B, fty = T1y + C, ftz = A - T1z;
        T1x = 2.f*B + T2x;  T1y = 2.f*C + T2y;  T1z = T2z;
        T2x = B;  T2y = C;  T2z = A;

        if (p >= 2) {   // output plane z0 + (p-2) finalized
            // fused: (pm-tm)^2 = a+b-2*sqrt(ab);  rsq(np2)*rsq(nt2)=rsq(np2*nt2)
            const v2 np2 = fpx*fpx + fpy*fpy + fpz*fpz;
            const v2 nt2 = ftx*ftx + fty*fty + ftz*ftz;
            const v2 a  = np2 + 1e-8f;
            const v2 bb = nt2 + 1e-8f;
            const v2 ab = a * bb;
            v2 rt;
            rt.x = __builtin_amdgcn_sqrtf(ab.x);
            rt.y = __builtin_amdgcn_sqrtf(ab.y);
            accm += a + bb - 2.f*rt;
            const v2 dt = fpx*ftx + fpy*fty + fpz*ftz;
            v2 pr = np2 * nt2;
            pr.x = fmaxf(pr.x, 1e-30f);
            pr.y = fmaxf(pr.y, 1e-30f);
            v2 rq;
            rq.x = __builtin_amdgcn_rsqf(pr.x);
            rq.y = __builtin_amdgcn_rsqf(pr.y);
            accc += dt * rq;
        }

        // one barrier per plane: (a) next plane's staged data landed (vmcnt
        // drain), (b) all reads of buf done before iter p+2 overwrites it.
        __syncthreads();
    }

    // ---- block reduction ----
    float am = accm.x + accm.y;
    float ac = accc.x + accc.y;
    #pragma unroll
    for (int off = 32; off >= 1; off >>= 1) {
        am += __shfl_down(am, off);
        ac += __shfl_down(ac, off);
    }
    if ((tid & 63) == 0) { rred[wid] = am; rred[4 + wid] = ac; }
    __syncthreads();
    if (tid == 0) {
        const float m = rred[0] + rred[1] + rred[2] + rred[3];
        const float c = rred[4] + rred[5] + rred[6] + rred[7];
        partial[bid] = make_float2(m, c);
    }
}

__global__ __launch_bounds__(256)
void acl_final(const float2* __restrict__ partial, float* __restrict__ out)
{
    __shared__ double sm[256], sc[256];
    double m = 0.0, c = 0.0;
    for (int i = threadIdx.x; i < NBLOCKS; i += 256) {
        const float2 v = partial[i];
        m += (double)v.x;
        c += (double)v.y;
    }
    sm[threadIdx.x] = m;
    sc[threadIdx.x] = c;
    __syncthreads();
    #pragma unroll
    for (int s = 128; s >= 1; s >>= 1) {
        if (threadIdx.x < (unsigned)s) {
            sm[threadIdx.x] += sm[threadIdx.x + s];
            sc[threadIdx.x] += sc[threadIdx.x + s];
        }
        __syncthreads();
    }
    if (threadIdx.x == 0) {
        const double mag_loss = sm[0] / NVOX;
        const double dir_loss = 1.0 - sc[0] / NVOX;
        out[0] = (float)(0.2 * (mag_loss + dir_loss));
    }
}

extern "C" void kernel_launch(void* const* d_in, const int* in_sizes, int n_in,
                              void* d_out, int out_size, void* d_ws, size_t ws_size,
                              hipStream_t stream) {
    const float* pred = (const float*)d_in[0];
    const float* targ = (const float*)d_in[1];
    float* out = (float*)d_out;
    float2* partial = (float2*)d_ws;  // 1000 * 8 B = 8 KB

    acl_partial<<<NBLOCKS, 256, 0, stream>>>(pred, targ, partial);
    acl_final<<<1, 256, 0, stream>>>(partial, out);
}